// Round 9
// baseline (549.982 us; speedup 1.0000x reference)
//
#include <hip/hip_runtime.h>

#define BB 2
#define CC 256
#define NN 3600
#define NCH 2
#define HO 473
#define WO 473
#define NR 3712          // NN padded to mult of 128 (rows AND K-dim of S)
#define NTI 29           // tiles of 128 covering NN
#define ZKI 29           // K iters of 128 covering NR (gemm_z)
#define ZKS 4            // split-K slices for Z GEMMs (464 blocks = all-resident at 2/CU)
#define CZKS 3           // split-K slices for convs (= one dh row per slice)

typedef unsigned short u16;
typedef __attribute__((ext_vector_type(8))) short short8;
typedef __attribute__((ext_vector_type(4))) float f32x4;

static __device__ __forceinline__ u16 f2bf(float f) {
    unsigned u = __float_as_uint(f);
    unsigned r = (u + 0x7FFF + ((u >> 16) & 1)) >> 16;
    return (u16)r;
}
static __device__ __forceinline__ u16 f2h(float f) {
    _Float16 h = (_Float16)f;
    return __builtin_bit_cast(unsigned short, h);
}
static __device__ __forceinline__ float h2f(u16 u) {
    _Float16 h = __builtin_bit_cast(_Float16, u);
    return (float)h;
}

// async global->LDS, 16B per lane. LDS dest = wave-uniform base + lane*16.
static __device__ __forceinline__ void glds16(const u16* g, u16* l) {
    __builtin_amdgcn_global_load_lds(
        (const __attribute__((address_space(1))) void*)g,
        (__attribute__((address_space(3))) void*)l, 16, 0, 0);
}

// LDS tiles XOR-swizzled in 16B units within each 64-col half:
// slot' = slot ^ (row&7). Staged by loading global chunk (slot^(row&7)) into
// linear LDS slot; read back with the same XOR -> identity round trip,
// conflict-free ds_read_b128 (verified: SQ_LDS_BANK_CONFLICT == 0).

// ---------------------------------------------------------------------------
// 128x128 bf16 GEMM (gemm_we only): C[m][n] = sum_k A[m][k]*B[n][k], bf16 out
// ---------------------------------------------------------------------------
__global__ __launch_bounds__(256)
void gemm_we(const u16* __restrict__ vat, const u16* __restrict__ web,
             u16* __restrict__ wgtb)
{
    __shared__ u16 As[128 * 64];
    __shared__ u16 Bs[128 * 64];
    const u16* A = vat + (long)blockIdx.z * NR * CC;
    u16* Cp = wgtb + (long)blockIdx.z * NR * CC;

    const int t = threadIdx.x;
    const int w = t >> 6, lane = t & 63;
    const int mh = (w >> 1) * 64, nh = (w & 1) * 64;
    const int lm = lane & 15, quad = lane >> 4;
    const int m0 = blockIdx.y * 128, n0 = blockIdx.x * 128;
    const int wb = t & 192;

    f32x4 acc[4][4] = {};

    for (int k0 = 0; k0 < CC; k0 += 64) {
#pragma unroll
        for (int i = 0; i < 4; ++i) {
            int idx = i * 256 + t;
            int row = idx >> 3;
            int sc8 = ((idx ^ row) & 7) * 8;
            glds16(A + (long)(m0 + row) * CC + k0 + sc8, &As[(i * 256 + wb) * 8]);
            glds16(web + (long)(n0 + row) * CC + k0 + sc8, &Bs[(i * 256 + wb) * 8]);
        }
        __syncthreads();
#pragma unroll
        for (int s = 0; s < 2; ++s) {
            short8 a[4], b[4];
#pragma unroll
            for (int i = 0; i < 4; ++i)
                a[i] = *(const short8*)(&As[(mh + i * 16 + lm) * 64 + ((s * 4 + quad) ^ (lm & 7)) * 8]);
#pragma unroll
            for (int j = 0; j < 4; ++j)
                b[j] = *(const short8*)(&Bs[(nh + j * 16 + lm) * 64 + ((s * 4 + quad) ^ (lm & 7)) * 8]);
#pragma unroll
            for (int i = 0; i < 4; ++i)
#pragma unroll
                for (int j = 0; j < 4; ++j)
                    acc[i][j] = __builtin_amdgcn_mfma_f32_16x16x32_bf16(a[i], b[j], acc[i][j], 0, 0, 0);
        }
        __syncthreads();
    }
#pragma unroll
    for (int i = 0; i < 4; ++i)
#pragma unroll
        for (int r = 0; r < 4; ++r) {
            int row = m0 + mh + i * 16 + quad * 4 + r;
            if (row < NN)
#pragma unroll
                for (int j = 0; j < 4; ++j) {
                    int col = n0 + nh + j * 16 + lm;
                    if (col < CC) Cp[(long)row * CC + col] = f2bf(acc[i][j][r]);
                }
        }
}

// ---------------------------------------------------------------------------
// S GEMM with fused softmax-stat partials + dual fp16 output (S and S^T).
// Both S and S^T stores go through the LDS transpose buffer -> uint4-coalesced.
// S arrays have stride NR (K padded to 29x128 for gemm_z's BK=128).
// ---------------------------------------------------------------------------
__global__ __launch_bounds__(256)
void gemm_s_stats(const u16* __restrict__ A, const u16* __restrict__ B,
                  u16* __restrict__ Sh, u16* __restrict__ STh,
                  float* __restrict__ prowm, float* __restrict__ prows,
                  float* __restrict__ pcolm, float* __restrict__ pcols)
{
    __shared__ u16 smem[17408];           // As(8192) | Bs(8192); reused for tr/stats
    u16* As = smem;
    u16* Bs = smem + 8192;

    const int t = threadIdx.x;
    const int w = t >> 6, lane = t & 63;
    const int mh = (w >> 1) * 64, nh = (w & 1) * 64;
    const int lm = lane & 15, quad = lane >> 4;
    const int m0 = blockIdx.y * 128, n0 = blockIdx.x * 128;
    const int wb = t & 192;

    f32x4 acc[4][4] = {};

    for (int k0 = 0; k0 < CC; k0 += 64) {
#pragma unroll
        for (int i = 0; i < 4; ++i) {
            int idx = i * 256 + t;
            int row = idx >> 3;
            int sc8 = ((idx ^ row) & 7) * 8;
            glds16(A + (long)(m0 + row) * CC + k0 + sc8, &As[(i * 256 + wb) * 8]);
            glds16(B + (long)(n0 + row) * CC + k0 + sc8, &Bs[(i * 256 + wb) * 8]);
        }
        __syncthreads();
#pragma unroll
        for (int s = 0; s < 2; ++s) {
            short8 a[4], b[4];
#pragma unroll
            for (int i = 0; i < 4; ++i)
                a[i] = *(const short8*)(&As[(mh + i * 16 + lm) * 64 + ((s * 4 + quad) ^ (lm & 7)) * 8]);
#pragma unroll
            for (int j = 0; j < 4; ++j)
                b[j] = *(const short8*)(&Bs[(nh + j * 16 + lm) * 64 + ((s * 4 + quad) ^ (lm & 7)) * 8]);
#pragma unroll
            for (int i = 0; i < 4; ++i)
#pragma unroll
                for (int j = 0; j < 4; ++j)
                    acc[i][j] = __builtin_amdgcn_mfma_f32_16x16x32_bf16(a[i], b[j], acc[i][j], 0, 0, 0);
        }
        __syncthreads();
    }

    u16* tr = smem;                   // 128*136 u16 = 34816 B (fits exactly)

    // ---- S store via LDS transpose: tr[m_local][n_local] -> coalesced uint4 ----
#pragma unroll
    for (int i = 0; i < 4; ++i)
#pragma unroll
        for (int j = 0; j < 4; ++j)
#pragma unroll
            for (int r = 0; r < 4; ++r)
                tr[(mh + i * 16 + quad * 4 + r) * 136 + (nh + j * 16 + lm)] = f2h(acc[i][j][r]);
    __syncthreads();
    {
        int row = t >> 1, hf = t & 1;
        int ng = m0 + row;
        if (ng < NN) {
#pragma unroll
            for (int q = 0; q < 8; ++q) {
                int cb = n0 + hf * 64 + q * 8;
                if (cb < NN)
                    *(uint4*)(&Sh[(long)ng * NR + cb]) =
                        *(const uint4*)(&tr[row * 136 + hf * 64 + q * 8]);
            }
        }
    }
    __syncthreads();

    // ---- fused stats ----
    bool cval[4];
#pragma unroll
    for (int j = 0; j < 4; ++j) cval[j] = (n0 + nh + j * 16 + lm) < NN;

    float* sm = (float*)smem;         // 4 x [2][128] floats = 4 KB
    float* rowm = sm;
    float* rows_ = sm + 256;
    float* colm = sm + 512;
    float* cols_ = sm + 768;

    // row stats (over this block's cols)
#pragma unroll
    for (int i = 0; i < 4; ++i)
#pragma unroll
        for (int r = 0; r < 4; ++r) {
            float m = -3.0e38f;
#pragma unroll
            for (int j = 0; j < 4; ++j) if (cval[j]) m = fmaxf(m, acc[i][j][r]);
            m = fmaxf(m, __shfl_xor(m, 1, 64));
            m = fmaxf(m, __shfl_xor(m, 2, 64));
            m = fmaxf(m, __shfl_xor(m, 4, 64));
            m = fmaxf(m, __shfl_xor(m, 8, 64));
            float s = 0.f;
#pragma unroll
            for (int j = 0; j < 4; ++j) if (cval[j]) s += __expf(acc[i][j][r] - m);
            s += __shfl_xor(s, 1, 64);
            s += __shfl_xor(s, 2, 64);
            s += __shfl_xor(s, 4, 64);
            s += __shfl_xor(s, 8, 64);
            if (lm == 0) {
                int rr = mh + i * 16 + quad * 4 + r;
                rowm[(w & 1) * 128 + rr] = m;
                rows_[(w & 1) * 128 + rr] = s;
            }
        }

    // col stats (over this block's rows)
#pragma unroll
    for (int j = 0; j < 4; ++j) {
        float m = -3.0e38f;
#pragma unroll
        for (int i = 0; i < 4; ++i)
#pragma unroll
            for (int r = 0; r < 4; ++r)
                if (m0 + mh + i * 16 + quad * 4 + r < NN) m = fmaxf(m, acc[i][j][r]);
        m = fmaxf(m, __shfl_xor(m, 16, 64));
        m = fmaxf(m, __shfl_xor(m, 32, 64));
        float s = 0.f;
#pragma unroll
        for (int i = 0; i < 4; ++i)
#pragma unroll
            for (int r = 0; r < 4; ++r)
                if (m0 + mh + i * 16 + quad * 4 + r < NN) s += __expf(acc[i][j][r] - m);
        s += __shfl_xor(s, 16, 64);
        s += __shfl_xor(s, 32, 64);
        if (quad == 0) {
            int ccl = nh + j * 16 + lm;
            colm[(w >> 1) * 128 + ccl] = m;
            cols_[(w >> 1) * 128 + ccl] = s;
        }
    }
    __syncthreads();

    if (t < 128) {
        float m1 = rowm[t], m2 = rowm[128 + t];
        float M = fmaxf(m1, m2);
        float s = rows_[t] * __expf(m1 - M) + rows_[128 + t] * __expf(m2 - M);
        if (m0 + t < NN) {
            prowm[(long)blockIdx.x * NR + m0 + t] = M;
            prows[(long)blockIdx.x * NR + m0 + t] = s;
        }
    } else {
        int c = t - 128;
        float m1 = colm[c], m2 = colm[128 + c];
        float M = fmaxf(m1, m2);
        float s = cols_[c] * __expf(m1 - M) + cols_[128 + c] * __expf(m2 - M);
        if (n0 + c < NN) {
            pcolm[(long)blockIdx.y * NR + n0 + c] = M;
            pcols[(long)blockIdx.y * NR + n0 + c] = s;
        }
    }

    // ---- S^T via LDS transpose: tr[n_local][m_local] ----
    __syncthreads();
#pragma unroll
    for (int i = 0; i < 4; ++i)
#pragma unroll
        for (int j = 0; j < 4; ++j)
#pragma unroll
            for (int r = 0; r < 4; ++r)
                tr[(nh + j * 16 + lm) * 136 + (mh + i * 16 + quad * 4 + r)] = f2h(acc[i][j][r]);
    __syncthreads();
    {
        int row = t >> 1, hf = t & 1;
        int mg = n0 + row;
        if (mg < NN) {
#pragma unroll
            for (int q = 0; q < 8; ++q) {
                int cb = m0 + hf * 64 + q * 8;
                if (cb < NN)
                    *(uint4*)(&STh[(long)mg * NR + cb]) =
                        *(const uint4*)(&tr[row * 136 + hf * 64 + q * 8]);
            }
        }
    }
}

// ---------------------------------------------------------------------------
// Merge the NTI per-tile partials -> final (max, 1/sum) per row/col.
// y=0: rows (for Sh), y=1: cols (for STh). ~0.9 MB read, trivially fast.
// ---------------------------------------------------------------------------
__global__ __launch_bounds__(256)
void stats_final(const float* __restrict__ prm, const float* __restrict__ prs,
                 const float* __restrict__ pcm, const float* __restrict__ pcs,
                 float* __restrict__ rm, float* __restrict__ ri,
                 float* __restrict__ cm, float* __restrict__ ci)
{
    int i = blockIdx.x * 256 + threadIdx.x;
    if (i >= NN) return;
    const float* pm = blockIdx.y ? pcm : prm;
    const float* ps = blockIdx.y ? pcs : prs;
    float m = -3.0e38f, s = 0.f;
#pragma unroll 4
    for (int tI = 0; tI < NTI; ++tI) {
        float m2 = pm[(long)tI * NR + i], s2 = ps[(long)tI * NR + i];
        float M = fmaxf(m, m2);
        s = s * __expf(m - M) + s2 * __expf(m2 - M);
        m = M;
    }
    float inv = 1.f / s;
    if (blockIdx.y) { cm[i] = m; ci[i] = inv; }
    else            { rm[i] = m; ri[i] = inv; }
}

// ---------------------------------------------------------------------------
// Z GEMM with FUSED softmax, BK=128 (round-8 structure, unchanged).
// ---------------------------------------------------------------------------
__global__ __launch_bounds__(256, 2)
void gemm_z_128(const u16* __restrict__ vab_b, const u16* __restrict__ vbb_b,
                const u16* __restrict__ STh, const u16* __restrict__ Sh,
                const float* __restrict__ rm, const float* __restrict__ ri,
                const float* __restrict__ cm, const float* __restrict__ ci,
                float* __restrict__ Zb_b, float* __restrict__ Za_b)
{
    __shared__ u16 As[128 * 128];
    __shared__ u16 Bs[128 * 128];

    const int t = threadIdx.x;
    const int w = t >> 6, lane = t & 63;
    const int mh = (w >> 1) * 64, nh = (w & 1) * 64;
    const int lm = lane & 15, quad = lane >> 4;
    const int n0 = blockIdx.x * 128;
    const int ks = blockIdx.y;                  // 0..3
    const int zz = blockIdx.z;
    const int branch = zz & 1;
    const int m0 = (zz >> 1) * 128;
    const u16* A = branch ? vbb_b : vab_b;
    const u16* B = branch ? Sh : STh;           // raw fp16 S / S^T, stride NR
    const float* mxp = branch ? rm : cm;
    const float* isp = branch ? ri : ci;
    float* Cp = branch ? Za_b : Zb_b;
    const int wb = t & 192;

    const int base = ZKI / ZKS, rem = ZKI % ZKS;   // 7, 1
    const int it0 = ks * base + (ks < rem ? ks : rem);
    const int itn = base + (ks < rem ? 1 : 0);

    // loop-invariant staging geometry: 8 slices over [128 rows][16 chunks].
    int scv[8];
    const u16* Arow[8];
    const u16* Brow[8];
    float bm[8], bi[8];
#pragma unroll
    for (int i = 0; i < 8; ++i) {
        int idx = i * 256 + t;
        int row = idx >> 4, c = idx & 15;
        scv[i] = (c & 8) * 8 + ((c ^ row) & 7) * 8;   // u16 offset in 128-col window
        Arow[i] = A + (long)(m0 + row) * NR + scv[i];
        int rg = n0 + row;
        Brow[i] = B + (long)rg * NR + scv[i];
        int rc = rg < NN ? rg : 0;             // pad rows: value discarded by preds
        bm[i] = mxp[rc];
        bi[i] = isp[rc];
    }

    f32x4 acc[4][4] = {};

    for (int it = it0; it < it0 + itn; ++it) {
        const int k0 = it * 128;
#pragma unroll
        for (int i = 0; i < 8; ++i)
            glds16(Arow[i] + k0, &As[(i * 256 + wb) * 8]);
#pragma unroll
        for (int i = 0; i < 8; ++i) {
            u16 o[8];
            uint4 v = *(const uint4*)(Brow[i] + k0);   // always in-bounds (NRxNR)
            const u16* hp = (const u16*)&v;
            if (k0 + scv[i] < NN) {            // chunk fully < NN (granularity 8)
#pragma unroll
                for (int e = 0; e < 8; ++e)
                    o[e] = f2bf(__expf(h2f(hp[e]) - bm[i]) * bi[i]);
            } else {
#pragma unroll
                for (int e = 0; e < 8; ++e) o[e] = 0;
            }
            *(uint4*)(&Bs[(i * 256 + t) * 8]) = *(const uint4*)o;
        }
        __syncthreads();
#pragma unroll
        for (int s = 0; s < 4; ++s) {          // 4 K-substeps of 32 -> 64 MFMA
            const int sl = ((s >> 1) * 8 + (((s & 1) * 4 + quad) ^ (lm & 7))) * 8;
            short8 a[4], b[4];
#pragma unroll
            for (int i = 0; i < 4; ++i)
                a[i] = *(const short8*)(&As[(mh + i * 16 + lm) * 128 + sl]);
#pragma unroll
            for (int j = 0; j < 4; ++j)
                b[j] = *(const short8*)(&Bs[(nh + j * 16 + lm) * 128 + sl]);
#pragma unroll
            for (int i = 0; i < 4; ++i)
#pragma unroll
                for (int j = 0; j < 4; ++j)
                    acc[i][j] = __builtin_amdgcn_mfma_f32_16x16x32_bf16(a[i], b[j], acc[i][j], 0, 0, 0);
        }
        __syncthreads();
    }

#pragma unroll
    for (int i = 0; i < 4; ++i)
#pragma unroll
        for (int r = 0; r < 4; ++r) {
            int row = m0 + mh + i * 16 + quad * 4 + r;
#pragma unroll
            for (int j = 0; j < 4; ++j) {
                int col = n0 + nh + j * 16 + lm;
                if (col < NN)
                    atomicAdd(&Cp[(long)row * NN + col], acc[i][j][r]);
            }
        }
}

// ---------------------------------------------------------------------------
// Both direct convs, one launch, BK=128 (mirrors gemm_z's proven structure):
// 64 MFMA per barrier-drain, 64 KB LDS, single-buffer lockstep. Weight layout
// is dh-slice-major, dw-OUTER within slice (g = dw*PCN + pc; PCN even -> each
// 128-col tile has ONE dw, uniform per iteration). dw advances by counter.
// Per-lane half (t>>3)&1 selects the 64-col group -> (plane, cip).
// XCD-grouped remap combo = L%8 (round-5 mapping, frozen). CZKS=3 (dh/slice).
// ---------------------------------------------------------------------------
__global__ __launch_bounds__(256, 2)
void conv_both(const u16* __restrict__ W1, const u16* __restrict__ W2,
               const u16* __restrict__ gzaT, const u16* __restrict__ vat,
               const u16* __restrict__ daT, const u16* __restrict__ gzbT,
               const u16* __restrict__ vbt, const u16* __restrict__ zbuf,
               float* __restrict__ y1, float* __restrict__ y2)
{
    __shared__ u16 As[128 * 128];
    __shared__ u16 Bs[128 * 128];

    const int t = threadIdx.x;
    const int w = t >> 6, lane = t & 63;
    const int mh = (w >> 1) * 64, nh = (w & 1) * 64;
    const int lm = lane & 15, quad = lane >> 4;
    const int wb = t & 192;

    const long L = blockIdx.x + (long)NTI * (blockIdx.y + (long)CZKS * blockIdx.z);
    const int combo = (int)(L & 7);
    const long rest = L >> 3;                   // 0..86
    const int ks = (int)(rest % CZKS);
    const int px = (int)(rest / CZKS);          // 0..28
    const int which = combo >> 2;
    const int b = (combo >> 1) & 1;
    const int m0 = (combo & 1) * 128;
    const int n0 = px * 128;

    const int CIN = which ? 512 : 768;
    const int KT = 9 * CIN;
    const int PCN2 = CIN >> 7;                  // 128-col groups per dw: 6 or 4
    const int PER2 = 3 * PCN2;                  // BK=128 iters per slice: 18 or 12
    const u16* W = which ? W2 : W1;
    const u16* P0 = which ? gzbT : gzaT;
    const u16* P1 = which ? vbt : vat;
    const u16* P2 = which ? vbt : daT;
    float* Y = which ? y2 : y1;
    const long pstride = (long)NR * CC;

    const int dh = ks - 1;                      // block-constant
    const int half = (t >> 3) & 1;              // lane's 64-col half of the tile

    // hoisted per-slice staging geometry (row = i*16 + (t>>4), c = t&15)
    long aoff[8];
    int pb[8], okb[8];
#pragma unroll
    for (int i = 0; i < 8; ++i) {
        int row = i * 16 + (t >> 4);
        int slot8 = (((t & 7) ^ row) & 7) * 8;  // swizzled 16B slot within half
        aoff[i] = (long)(m0 + row) * KT + half * 64 + slot8;
        int p = n0 + row;
        int h = p / 60, wp = p - h * 60;
        bool hok = (p < NN) && ((unsigned)(h + dh) < 60u);
        int ob = 0;
#pragma unroll
        for (int d = 0; d < 3; ++d)
            if (hok && ((unsigned)(wp + d - 1) < 60u)) ob |= (1 << d);
        okb[i] = ob;
        pb[i] = (p + dh * 60 - 1) * CC + slot8; // + dwi*CC + cip added per iter
    }

    f32x4 acc[4][4] = {};

    int dwi = 0, pcp = 0;                       // dw index / pc-pair counters
    const long wslice = (long)ks * (3 * CIN);   // weight col base of slice (u16)
    for (int it = 0; it < PER2; ++it) {
        const long k0 = wslice + (long)it * 128;
        const int pcl = 2 * pcp + half;         // lane's 64-col channel group
        const int plane = pcl >> 2;
        const u16* sp = (plane == 0) ? P0 : (plane == 1) ? P1 : P2;
        const u16* sbase = sp + (long)b * pstride + dwi * CC + ((pcl & 3) << 6);

#pragma unroll
        for (int i = 0; i < 8; ++i) {
            glds16(W + aoff[i] + k0, &As[(i * 256 + wb) * 8]);
            const u16* gs = ((okb[i] >> dwi) & 1) ? sbase + pb[i] : zbuf;
            glds16(gs, &Bs[(i * 256 + wb) * 8]);
        }
        __syncthreads();
#pragma unroll
        for (int s = 0; s < 4; ++s) {           // 4 K-substeps of 32 -> 64 MFMA
            const int sl = ((s >> 1) * 8 + (((s & 1) * 4 + quad) ^ (lm & 7))) * 8;
            short8 a[4], bfr[4];
#pragma unroll
            for (int i = 0; i < 4; ++i)
                a[i] = *(const short8*)(&As[(mh + i * 16 + lm) * 128 + sl]);
#pragma unroll
            for (int j = 0; j < 4; ++j)
                bfr[j] = *(const short8*)(&Bs[(nh + j * 16 + lm) * 128 + sl]);
#pragma unroll
            for (int i = 0; i < 4; ++i)
#pragma unroll
                for (int j = 0; j < 4; ++j)
                    acc[i][j] = __builtin_amdgcn_mfma_f32_16x16x32_bf16(a[i], bfr[j], acc[i][j], 0, 0, 0);
        }
        __syncthreads();
        if (++pcp == PCN2) { pcp = 0; ++dwi; }
    }

    float* out = Y + (long)b * CC * NN;
#pragma unroll
    for (int i = 0; i < 4; ++i)
#pragma unroll
        for (int r = 0; r < 4; ++r) {
            int row = m0 + mh + i * 16 + quad * 4 + r;
#pragma unroll
            for (int j = 0; j < 4; ++j) {
                int col = n0 + nh + j * 16 + lm;
                if (col < NN)
                    atomicAdd(&out[(long)row * NN + col], acc[i][j][r]);
            }
        }
}

// ---------------------------------------------------------------------------
// Converters / transposes
// ---------------------------------------------------------------------------
__global__ __launch_bounds__(256)
void cvt_we(const float* __restrict__ W, u16* __restrict__ O)
{
    int i = blockIdx.x * 256 + threadIdx.x;
    if (i < CC * CC) O[i] = f2bf(W[i]);
}

// All three input transposes in one launch: z -> (src, batch).
// V [b][256][3600] fp32 -> VT [b][3712][256] bf16 (+ optional NR-padded copy
// with zeroed cols 3600..3712 for gemm_z's BK=128). grid.x = 58.
__global__ __launch_bounds__(256)
void transpose_cvt3(const float* __restrict__ Va, const float* __restrict__ Vb,
                    const float* __restrict__ Da,
                    u16* __restrict__ vat, u16* __restrict__ vbt,
                    u16* __restrict__ daT,
                    u16* __restrict__ vab, u16* __restrict__ vbb)
{
    __shared__ float tile[64][65];
    int z = blockIdx.z;
    int s = z % 3, b = z / 3;
    const float* V = (s == 0) ? Va : (s == 1) ? Vb : Da;
    u16* VT = (s == 0) ? vat : (s == 1) ? vbt : daT;
    u16* Vpad = (s == 0) ? vab : (s == 1) ? vbb : nullptr;

    int c0 = blockIdx.y * 64, n0 = blockIdx.x * 64;
    int t = threadIdx.x;
#pragma unroll
    for (int e = 0; e < 16; ++e) {
        int f = e * 256 + t; int i = f >> 6, j = f & 63;
        int n = n0 + j;
        float v = 0.f;
        if (n < NN) v = V[((long)b * CC + c0 + i) * NN + n];
        tile[i][j] = v;
        if (Vpad) Vpad[((long)b * CC + c0 + i) * NR + n] = f2bf(v);
    }
    __syncthreads();
#pragma unroll
    for (int e = 0; e < 16; ++e) {
        int f = e * 256 + t; int i = f >> 6, j = f & 63;
        int n = n0 + i;
        if (n < NN) VT[((long)b * NR + n) * CC + c0 + j] = f2bf(tile[j][i]);
    }
}

// conv weight convert, dh-slice-major / dw-OUTER permutation (matches
// conv_both BK=128): c64 group -> ks = c64/PER, g = c64%PER, dw = g/PCN,
// pc = g%PCN; tap = ks*3+dw, ci = pc*64+within.
template<int CIN>
__global__ __launch_bounds__(256)
void cvt_convw(const float* __restrict__ W, u16* __restrict__ O)
{
    const int KT = 9 * CIN;
    const int PCN = CIN / 64;
    const int PER = 3 * PCN;
    long idx = (long)blockIdx.x * 256 + threadIdx.x;
    if (idx >= (long)CC * KT) return;
    int co = (int)(idx / KT);
    int r = (int)(idx % KT);
    int c64 = r >> 6, within = r & 63;
    int ks = c64 / PER, g = c64 % PER;
    int dw = g / PCN, pc = g % PCN;
    int tap = ks * 3 + dw;
    int ci = pc * 64 + within;
    O[idx] = f2bf(W[((long)co * CIN + ci) * 9 + tap]);
}

// ---------------------------------------------------------------------------
// FUSED per-pixel gate + transpose-scale: one pass computes
// sg[p] = sigmoid(sum_c gw[c]*Z[c,p]) for the block's 64 pixels, then the
// 4 transpose sub-tiles re-read the block's 64 KB window (L2-hot) and write
// ZT[b][p][c] = bf16(Z[c,p] * sg[p]). Halves Z's HBM reads vs the old
// gate_sig + transpose_gate pair. blockIdx.y: b = y&1, side = y>>1.
// ---------------------------------------------------------------------------
__global__ __launch_bounds__(256)
void gate_transpose(const float* __restrict__ Za, const float* __restrict__ Zb,
                    const float* __restrict__ gw,
                    u16* __restrict__ gzaT, u16* __restrict__ gzbT)
{
    __shared__ float tile[64][65];
    __shared__ float red[256];
    __shared__ float sgs[64];

    int zy = blockIdx.y;
    int b = zy & 1, ab = zy >> 1;
    const float* Z = ab ? Zb : Za;
    u16* ZT = ab ? gzbT : gzaT;
    int n0 = blockIdx.x * 64;
    int t = threadIdx.x;
    int px = t & 63, ck = t >> 6;
    const float* Zp = Z + (long)b * CC * NN;

    // gate reduction (all 256 channels across 4 thread-groups)
    float g = 0.f;
    int p = n0 + px;
    if (p < NN) {
        for (int c = ck * 64; c < ck * 64 + 64; ++c) g += gw[c] * Zp[(long)c * NN + p];
    }
    red[t] = g;
    __syncthreads();
    if (t < 64) {
        float tot = red[t] + red[t + 64] + red[t + 128] + red[t + 192];
        sgs[t] = 1.f / (1.f + __expf(-tot));
    }

    // 4 transpose sub-tiles (re-read through L2)
    for (int c0 = 0; c0 < CC; c0 += 64) {
        __syncthreads();
#pragma unroll
        for (int e = 0; e < 16; ++e) {
            int f = e * 256 + t; int i = f >> 6, j = f & 63;
            int n = n0 + j;
            float v = 0.f;
            if (n < NN) v = Zp[(long)(c0 + i) * NN + n];
            tile[i][j] = v;
        }
        __syncthreads();
#pragma unroll
        for (int e = 0; e < 16; ++e) {
            int f = e * 256 + t; int i = f >> 6, j = f & 63;
            int n = n0 + i;
            if (n < NN)
                ZT[((long)b * NR + n) * CC + c0 + j] = f2bf(tile[j][i] * sgs[i]);
        }
    }
}

// ---------------------------------------------------------------------------
// BatchNorm batch-stats -> scale/shift, both branches (x = which*256 + c)
// ---------------------------------------------------------------------------
__global__ __launch_bounds__(256)
void bn_stats_kernel(const float* __restrict__ y1, const float* __restrict__ y2,
                     const float* __restrict__ g1, const float* __restrict__ b1,
                     const float* __restrict__ g2, const float* __restrict__ b2,
                     float* __restrict__ sc1, float* __restrict__ sh1,
                     float* __restrict__ sc2, float* __restrict__ sh2)
{
    int which = blockIdx.x >> 8;
    int c = blockIdx.x & 255, t = threadIdx.x;
    const float* Y = which ? y2 : y1;
    const float* g = which ? g2 : g1;
    const float* beta = which ? b2 : b1;
    float* scale = which ? sc2 : sc1;
    float* shift = which ? sh2 : sh1;
    float s = 0.f, sq = 0.f;
    for (int b = 0; b < BB; ++b) {
        const float* p = Y + (long)b * CC * NN + (long)c * NN;
        for (int i = t; i < NN; i += 256) { float v = p[i]; s += v; sq += v * v; }
    }
    __shared__ float ls[256], lq[256];
    ls[t] = s; lq[t] = sq;
    __syncthreads();
    for (int off = 128; off > 0; off >>= 1) {
        if (t < off) { ls[t] += ls[t + off]; lq[t] += lq[t + off]; }
        __syncthreads();
    }
    if (t == 0) {
        const float inv = 1.f / (float)(BB * NN);
        float mean = ls[0] * inv;
        float var = fmaxf(lq[0] * inv - mean * mean, 0.f);
        float sc = g[c] * rsqrtf(var + 1e-5f);
        scale[c] = sc;
        shift[c] = beta[c] - mean * sc;
    }
}

// ---------------------------------------------------------------------------
// Fused BN-normalize + ReLU + 1x1 cls conv + bias, both branches (z = which)
// ---------------------------------------------------------------------------
__global__ __launch_bounds__(256)
void cls_kernel(const float* __restrict__ y1, const float* __restrict__ y2,
                const float* __restrict__ sc1, const float* __restrict__ sh1,
                const float* __restrict__ sc2, const float* __restrict__ sh2,
                const float* __restrict__ cw1, const float* __restrict__ cb1,
                const float* __restrict__ cw2, const float* __restrict__ cb2,
                float* __restrict__ O1, float* __restrict__ O2)
{
    int which = blockIdx.z;
    const float* Y = which ? y2 : y1;
    const float* scale = which ? sc2 : sc1;
    const float* shift = which ? sh2 : sh1;
    const float* cw = which ? cw2 : cw1;
    const float* cb = which ? cb2 : cb1;
    float* O = which ? O2 : O1;

    int t = threadIdx.x;
    int px = t & 63, ck = t >> 6;
    int b = blockIdx.y;
    int p = blockIdx.x * 64 + px;
    const float* Yb = Y + (long)b * CC * NN;
    float a0 = 0.f, a1 = 0.f;
    if (p < NN) {
        for (int c = ck * 64; c < ck * 64 + 64; ++c) {
            float v = Yb[(long)c * NN + p] * scale[c] + shift[c];
            v = fmaxf(v, 0.f);
            a0 += cw[c] * v;
            a1 += cw[CC + c] * v;
        }
    }
    __shared__ float r0[256], r1[256];
    r0[t] = a0; r1[t] = a1;
    __syncthreads();
    if (t < 64) {
        int pp = blockIdx.x * 64 + t;
        if (pp < NN) {
            float s0 = r0[t] + r0[t + 64] + r0[t + 128] + r0[t + 192];
            float s1 = r1[t] + r1[t + 64] + r1[t + 128] + r1[t + 192];
            O[(long)b * NCH * NN + pp] = s0 + cb[0];
            O[(long)b * NCH * NN + NN + pp] = s1 + cb[1];
        }
    }
}

// ---------------------------------------------------------------------------
// Bilinear resize 60x60 -> 473x473 (half-pixel, clamp) + sigmoid
// ---------------------------------------------------------------------------
__global__ __launch_bounds__(256)
void resize_sig_kernel(const float* __restrict__ I1, const float* __restrict__ I2,
                       float* __restrict__ O)
{
    const long HALF = (long)BB * NCH * HO * WO;
    long gid = (long)blockIdx.x * 256 + threadIdx.x;
    if (gid >= HALF) return;
    int half = blockIdx.y;
    const float* I = half ? I2 : I1;
    float* Op = O + half * HALF;

    int j = (int)(gid % WO);
    long r = gid / WO;
    int i = (int)(r % HO);
    int pc = (int)(r / HO);
    const float* ip = I + (long)pc * NN;

    const float SCL = 60.0f / 473.0f;
    float fy = (i + 0.5f) * SCL - 0.5f;
    float fx = (j + 0.5f) * SCL - 0.5f;
    int y0 = (int)floorf(fy);
    int x0 = (int)floorf(fx);
    float ty = fy - (float)y0;
    float tx = fx - (float)x0;
    int y0c = max(y0, 0), y1c = min(y0 + 1, 59);
    int x0c = max(x0, 0), x1c = min(x0 + 1, 59);
    float va = ip[y0c * 60 + x0c], vb = ip[y0c * 60 + x1c];
    float vc = ip[y1c * 60 + x0c], vd = ip[y1c * 60 + x1c];
    float v = (1.f - ty) * ((1.f - tx) * va + tx * vb) + ty * ((1.f - tx) * vc + tx * vd);
    Op[gid] = 1.f / (1.f + __expf(-v));
}

// ---------------------------------------------------------------------------
extern "C" void kernel_launch(void* const* d_in, const int* in_sizes, int n_in,
                              void* d_out, int out_size, void* d_ws, size_t ws_size,
                              hipStream_t stream)
{
    const float* V_a    = (const float*)d_in[0];
    const float* V_b    = (const float*)d_in[1];
    const float* D_a    = (const float*)d_in[2];
    const float* W_e    = (const float*)d_in[3];
    const float* gate_w = (const float*)d_in[4];
    const float* conv1_w = (const float*)d_in[5];
    const float* conv2_w = (const float*)d_in[6];
    const float* bn1_g = (const float*)d_in[7];
    const float* bn1_b = (const float*)d_in[8];
    const float* bn2_g = (const float*)d_in[9];
    const float* bn2_b = (const float*)d_in[10];
    const float* cls1_w = (const float*)d_in[11];
    const float* cls1_b = (const float*)d_in[12];
    const float* cls2_w = (const float*)d_in[13];
    const float* cls2_b = (const float*)d_in[14];
    float* out = (float*)d_out;

    // ---- workspace arena (~124 MB; known-safe bound: 154.9 MB) ----
    size_t off = 0;
    char* wsb = (char*)d_ws;
    auto carve = [&](size_t bytes) -> char* {
        char* p = wsb + off; off += (bytes + 255) & ~(size_t)255; return p;
    };

    u16* Sh    = (u16*)carve((size_t)NR * NR * 2);         // 27.6 MB, per-batch (raw S)
    u16* STh   = (u16*)carve((size_t)NR * NR * 2);         // 27.6 MB, per-batch (raw S^T)
    u16* vab   = (u16*)carve((size_t)BB * CC * NR * 2);    // K padded to NR, pads zeroed
    u16* vbb   = (u16*)carve((size_t)BB * CC * NR * 2);
    u16* vat   = (u16*)carve((size_t)BB * NR * CC * 2);
    u16* vbt   = (u16*)carve((size_t)BB * NR * CC * 2);
    u16* daT   = (u16*)carve((size_t)BB * NR * CC * 2);
    u16* gzaT  = (u16*)carve((size_t)BB * NR * CC * 2);
    u16* gzbT  = (u16*)carve((size_t)BB * NR * CC * 2);
    u16* wgtb  = (u16*)carve((size_t)BB * NR * CC * 2);
    u16* zbuf  = (u16*)carve(256);
    u16* web   = (u16*)carve((size_t)CC * CC * 2);
    u16* wt1   = (u16*)carve((size_t)CC * 9 * 768 * 2);
    u16* wt2   = (u16*)carve((size_t)CC * 9 * 512 * 2);
    float* Za  = (float*)carve((size_t)BB * CC * NN * 4);  // contiguous 4-block
    float* Zb  = (float*)carve((size_t)BB * CC * NN * 4);  //   memset region
    float* y1  = (float*)carve((size_t)BB * CC * NN * 4);
    float* y2  = (float*)carve((size_t)BB * CC * NN * 4);
    float* rmx = (float*)carve((size_t)BB * NN * 4);       // row max   (later BN sc1)
    float* rsm = (float*)carve((size_t)BB * NN * 4);       // row 1/sum (later BN sh1)
    float* cmx = (float*)carve((size_t)BB * NN * 4);       // col max   (later BN sc2)
    float* csm = (float*)carve((size_t)BB * NN * 4);       // col 1/sum (later BN sh2)
    float* prm = (float*)carve((size_t)NTI * NR * 4);
    float* prs = (float*)carve((size_t)NTI * NR * 4);
    float* pcm = (float*)carve((size_t)NTI * NR * 4);
    float* pcs = (float*)carve((size_t)NTI * NR * 4);
    float* c1o = (float*)carve((size_t)BB * NCH * NN * 4);
    float* c2o = (float*)carve((size_t)BB * NCH * NN * 4);

    dim3 blk(256);

    // zero-init atomic accumulators (Za,Zb,y1,y2 contiguous) + zbuf.
    // Pad rows of the transposed arenas are NOT zeroed — all consumers of
    // pad garbage are predicated (audited round 6).
    hipMemsetAsync(Za, 0, (size_t)4 * BB * CC * NN * 4, stream);
    hipMemsetAsync(zbuf, 0, 256, stream);

    // --- input conversions (merged; padded copies fused into transposes) ---
    cvt_we<<<256, blk, 0, stream>>>(W_e, web);
    transpose_cvt3<<<dim3(58, 4, 3 * BB), blk, 0, stream>>>(
        V_a, V_b, D_a, vat, vbt, daT, vab, vbb);
    cvt_convw<768><<<(int)(((long)CC * 9 * 768 + 255) / 256), blk, 0, stream>>>(conv1_w, wt1);
    cvt_convw<512><<<(int)(((long)CC * 9 * 512 + 255) / 256), blk, 0, stream>>>(conv2_w, wt2);

    // --- weighted (both batches) ---
    gemm_we<<<dim3(2, NTI, BB), blk, 0, stream>>>(vat, web, wgtb);

    // --- attention, per batch: S+stats -> final stats -> fused-softmax Z ---
    for (int b = 0; b < BB; ++b) {
        const u16* wgtb_b = wgtb + (long)b * NR * CC;
        const u16* vbt_b  = vbt + (long)b * NR * CC;
        const u16* vab_b  = vab + (long)b * CC * NR;
        const u16* vbb_b  = vbb + (long)b * CC * NR;
        float* rmx_b = rmx + b * NN; float* rsm_b = rsm + b * NN;
        float* cmx_b = cmx + b * NN; float* csm_b = csm + b * NN;

        gemm_s_stats<<<dim3(NTI, NTI), blk, 0, stream>>>(
            wgtb_b, vbt_b, Sh, STh, prm, prs, pcm, pcs);
        stats_final<<<dim3((NN + 255) / 256, 2), blk, 0, stream>>>(
            prm, prs, pcm, pcs, rmx_b, rsm_b, cmx_b, csm_b);
        gemm_z_128<<<dim3(NTI, ZKS, 4), blk, 0, stream>>>(
            vab_b, vbb_b, STh, Sh, rmx_b, rsm_b, cmx_b, csm_b,
            Zb + (long)b * CC * NN, Za + (long)b * CC * NN);
    }

    // --- fused gate sigmoid + transpose-scale to [p][c] bf16 ---
    gate_transpose<<<dim3(57, 2 * BB), blk, 0, stream>>>(
        Za, Zb, gate_w, gzaT, gzbT);

    // --- both convs, one launch, BK=128, XCD-grouped remap, atomic y1/y2 ---
    conv_both<<<dim3(NTI, CZKS, 8), blk, 0, stream>>>(
        wt1, wt2, gzaT, vat, daT, gzbT, vbt, zbuf, y1, y2);

    // --- BN + cls + resize --- (rmx/rsm/cmx/csm reused as scale/shift)
    bn_stats_kernel<<<2 * CC, blk, 0, stream>>>(
        y1, y2, bn1_g, bn1_b, bn2_g, bn2_b, rmx, rsm, cmx, csm);
    cls_kernel<<<dim3(57, BB, 2), blk, 0, stream>>>(
        y1, y2, rmx, rsm, cmx, csm, cls1_w, cls1_b, cls2_w, cls2_b, c1o, c2o);

    resize_sig_kernel<<<dim3((int)(((long)BB * NCH * HO * WO + 255) / 256), 2), blk, 0, stream>>>(c1o, c2o, out);
}

// Round 10
// 546.579 us; speedup vs baseline: 1.0062x; 1.0062x over previous
//
#include <hip/hip_runtime.h>

#define BB 2
#define CC 256
#define NN 3600
#define NCH 2
#define HO 473
#define WO 473
#define NR 3712          // NN padded to mult of 128 (rows AND K-dim of S)
#define NTI 29           // tiles of 128 covering NN
#define ZKI 29           // K iters of 128 covering NR (gemm_z)
#define ZKS 4            // split-K slices for Z GEMMs (464 blocks = all-resident at 2/CU)
#define CZKS 3           // split-K slices for convs (= one dh row per slice)

typedef unsigned short u16;
typedef __attribute__((ext_vector_type(8))) short short8;
typedef __attribute__((ext_vector_type(4))) float f32x4;

static __device__ __forceinline__ u16 f2bf(float f) {
    unsigned u = __float_as_uint(f);
    unsigned r = (u + 0x7FFF + ((u >> 16) & 1)) >> 16;
    return (u16)r;
}
static __device__ __forceinline__ u16 f2h(float f) {
    _Float16 h = (_Float16)f;
    return __builtin_bit_cast(unsigned short, h);
}
static __device__ __forceinline__ float h2f(u16 u) {
    _Float16 h = __builtin_bit_cast(_Float16, u);
    return (float)h;
}

// async global->LDS, 16B per lane. LDS dest = wave-uniform base + lane*16.
static __device__ __forceinline__ void glds16(const u16* g, u16* l) {
    __builtin_amdgcn_global_load_lds(
        (const __attribute__((address_space(1))) void*)g,
        (__attribute__((address_space(3))) void*)l, 16, 0, 0);
}

// LDS tiles XOR-swizzled in 16B units within each 64-col half:
// slot' = slot ^ (row&7). Staged by loading global chunk (slot^(row&7)) into
// linear LDS slot; read back with the same XOR -> identity round trip.

// ---------------------------------------------------------------------------
// 128x128 bf16 GEMM (gemm_we only): C[m][n] = sum_k A[m][k]*B[n][k], bf16 out
// ---------------------------------------------------------------------------
__global__ __launch_bounds__(256)
void gemm_we(const u16* __restrict__ vat, const u16* __restrict__ web,
             u16* __restrict__ wgtb)
{
    __shared__ u16 As[128 * 64];
    __shared__ u16 Bs[128 * 64];
    const u16* A = vat + (long)blockIdx.z * NR * CC;
    u16* Cp = wgtb + (long)blockIdx.z * NR * CC;

    const int t = threadIdx.x;
    const int w = t >> 6, lane = t & 63;
    const int mh = (w >> 1) * 64, nh = (w & 1) * 64;
    const int lm = lane & 15, quad = lane >> 4;
    const int m0 = blockIdx.y * 128, n0 = blockIdx.x * 128;
    const int wb = t & 192;

    f32x4 acc[4][4] = {};

    for (int k0 = 0; k0 < CC; k0 += 64) {
#pragma unroll
        for (int i = 0; i < 4; ++i) {
            int idx = i * 256 + t;
            int row = idx >> 3;
            int sc8 = ((idx ^ row) & 7) * 8;
            glds16(A + (long)(m0 + row) * CC + k0 + sc8, &As[(i * 256 + wb) * 8]);
            glds16(web + (long)(n0 + row) * CC + k0 + sc8, &Bs[(i * 256 + wb) * 8]);
        }
        __syncthreads();
#pragma unroll
        for (int s = 0; s < 2; ++s) {
            short8 a[4], b[4];
#pragma unroll
            for (int i = 0; i < 4; ++i)
                a[i] = *(const short8*)(&As[(mh + i * 16 + lm) * 64 + ((s * 4 + quad) ^ (lm & 7)) * 8]);
#pragma unroll
            for (int j = 0; j < 4; ++j)
                b[j] = *(const short8*)(&Bs[(nh + j * 16 + lm) * 64 + ((s * 4 + quad) ^ (lm & 7)) * 8]);
#pragma unroll
            for (int i = 0; i < 4; ++i)
#pragma unroll
                for (int j = 0; j < 4; ++j)
                    acc[i][j] = __builtin_amdgcn_mfma_f32_16x16x32_bf16(a[i], b[j], acc[i][j], 0, 0, 0);
        }
        __syncthreads();
    }
#pragma unroll
    for (int i = 0; i < 4; ++i)
#pragma unroll
        for (int r = 0; r < 4; ++r) {
            int row = m0 + mh + i * 16 + quad * 4 + r;
            if (row < NN)
#pragma unroll
                for (int j = 0; j < 4; ++j) {
                    int col = n0 + nh + j * 16 + lm;
                    if (col < CC) Cp[(long)row * CC + col] = f2bf(acc[i][j][r]);
                }
        }
}

// ---------------------------------------------------------------------------
// S GEMM with fused softmax-stat partials + dual fp16 output (S and S^T).
// Both S and S^T stores go through the LDS transpose buffer -> uint4-coalesced.
// S arrays have stride NR (K padded to 29x128 for gemm_z's BK=128).
// ---------------------------------------------------------------------------
__global__ __launch_bounds__(256)
void gemm_s_stats(const u16* __restrict__ A, const u16* __restrict__ B,
                  u16* __restrict__ Sh, u16* __restrict__ STh,
                  float* __restrict__ prowm, float* __restrict__ prows,
                  float* __restrict__ pcolm, float* __restrict__ pcols)
{
    __shared__ u16 smem[17408];           // As(8192) | Bs(8192); reused for tr/stats
    u16* As = smem;
    u16* Bs = smem + 8192;

    const int t = threadIdx.x;
    const int w = t >> 6, lane = t & 63;
    const int mh = (w >> 1) * 64, nh = (w & 1) * 64;
    const int lm = lane & 15, quad = lane >> 4;
    const int m0 = blockIdx.y * 128, n0 = blockIdx.x * 128;
    const int wb = t & 192;

    f32x4 acc[4][4] = {};

    for (int k0 = 0; k0 < CC; k0 += 64) {
#pragma unroll
        for (int i = 0; i < 4; ++i) {
            int idx = i * 256 + t;
            int row = idx >> 3;
            int sc8 = ((idx ^ row) & 7) * 8;
            glds16(A + (long)(m0 + row) * CC + k0 + sc8, &As[(i * 256 + wb) * 8]);
            glds16(B + (long)(n0 + row) * CC + k0 + sc8, &Bs[(i * 256 + wb) * 8]);
        }
        __syncthreads();
#pragma unroll
        for (int s = 0; s < 2; ++s) {
            short8 a[4], b[4];
#pragma unroll
            for (int i = 0; i < 4; ++i)
                a[i] = *(const short8*)(&As[(mh + i * 16 + lm) * 64 + ((s * 4 + quad) ^ (lm & 7)) * 8]);
#pragma unroll
            for (int j = 0; j < 4; ++j)
                b[j] = *(const short8*)(&Bs[(nh + j * 16 + lm) * 64 + ((s * 4 + quad) ^ (lm & 7)) * 8]);
#pragma unroll
            for (int i = 0; i < 4; ++i)
#pragma unroll
                for (int j = 0; j < 4; ++j)
                    acc[i][j] = __builtin_amdgcn_mfma_f32_16x16x32_bf16(a[i], b[j], acc[i][j], 0, 0, 0);
        }
        __syncthreads();
    }

    u16* tr = smem;                   // 128*136 u16 = 34816 B (fits exactly)

    // ---- S store via LDS transpose: tr[m_local][n_local] -> coalesced uint4 ----
#pragma unroll
    for (int i = 0; i < 4; ++i)
#pragma unroll
        for (int j = 0; j < 4; ++j)
#pragma unroll
            for (int r = 0; r < 4; ++r)
                tr[(mh + i * 16 + quad * 4 + r) * 136 + (nh + j * 16 + lm)] = f2h(acc[i][j][r]);
    __syncthreads();
    {
        int row = t >> 1, hf = t & 1;
        int ng = m0 + row;
        if (ng < NN) {
#pragma unroll
            for (int q = 0; q < 8; ++q) {
                int cb = n0 + hf * 64 + q * 8;
                if (cb < NN)
                    *(uint4*)(&Sh[(long)ng * NR + cb]) =
                        *(const uint4*)(&tr[row * 136 + hf * 64 + q * 8]);
            }
        }
    }
    __syncthreads();

    // ---- fused stats ----
    bool cval[4];
#pragma unroll
    for (int j = 0; j < 4; ++j) cval[j] = (n0 + nh + j * 16 + lm) < NN;

    float* sm = (float*)smem;         // 4 x [2][128] floats = 4 KB
    float* rowm = sm;
    float* rows_ = sm + 256;
    float* colm = sm + 512;
    float* cols_ = sm + 768;

    // row stats (over this block's cols)
#pragma unroll
    for (int i = 0; i < 4; ++i)
#pragma unroll
        for (int r = 0; r < 4; ++r) {
            float m = -3.0e38f;
#pragma unroll
            for (int j = 0; j < 4; ++j) if (cval[j]) m = fmaxf(m, acc[i][j][r]);
            m = fmaxf(m, __shfl_xor(m, 1, 64));
            m = fmaxf(m, __shfl_xor(m, 2, 64));
            m = fmaxf(m, __shfl_xor(m, 4, 64));
            m = fmaxf(m, __shfl_xor(m, 8, 64));
            float s = 0.f;
#pragma unroll
            for (int j = 0; j < 4; ++j) if (cval[j]) s += __expf(acc[i][j][r] - m);
            s += __shfl_xor(s, 1, 64);
            s += __shfl_xor(s, 2, 64);
            s += __shfl_xor(s, 4, 64);
            s += __shfl_xor(s, 8, 64);
            if (lm == 0) {
                int rr = mh + i * 16 + quad * 4 + r;
                rowm[(w & 1) * 128 + rr] = m;
                rows_[(w & 1) * 128 + rr] = s;
            }
        }

    // col stats (over this block's rows)
#pragma unroll
    for (int j = 0; j < 4; ++j) {
        float m = -3.0e38f;
#pragma unroll
        for (int i = 0; i < 4; ++i)
#pragma unroll
            for (int r = 0; r < 4; ++r)
                if (m0 + mh + i * 16 + quad * 4 + r < NN) m = fmaxf(m, acc[i][j][r]);
        m = fmaxf(m, __shfl_xor(m, 16, 64));
        m = fmaxf(m, __shfl_xor(m, 32, 64));
        float s = 0.f;
#pragma unroll
        for (int i = 0; i < 4; ++i)
#pragma unroll
            for (int r = 0; r < 4; ++r)
                if (m0 + mh + i * 16 + quad * 4 + r < NN) s += __expf(acc[i][j][r] - m);
        s += __shfl_xor(s, 16, 64);
        s += __shfl_xor(s, 32, 64);
        if (quad == 0) {
            int ccl = nh + j * 16 + lm;
            colm[(w >> 1) * 128 + ccl] = m;
            cols_[(w >> 1) * 128 + ccl] = s;
        }
    }
    __syncthreads();

    if (t < 128) {
        float m1 = rowm[t], m2 = rowm[128 + t];
        float M = fmaxf(m1, m2);
        float s = rows_[t] * __expf(m1 - M) + rows_[128 + t] * __expf(m2 - M);
        if (m0 + t < NN) {
            prowm[(long)blockIdx.x * NR + m0 + t] = M;
            prows[(long)blockIdx.x * NR + m0 + t] = s;
        }
    } else {
        int c = t - 128;
        float m1 = colm[c], m2 = colm[128 + c];
        float M = fmaxf(m1, m2);
        float s = cols_[c] * __expf(m1 - M) + cols_[128 + c] * __expf(m2 - M);
        if (n0 + c < NN) {
            pcolm[(long)blockIdx.y * NR + n0 + c] = M;
            pcols[(long)blockIdx.y * NR + n0 + c] = s;
        }
    }

    // ---- S^T via LDS transpose: tr[n_local][m_local] ----
    __syncthreads();
#pragma unroll
    for (int i = 0; i < 4; ++i)
#pragma unroll
        for (int j = 0; j < 4; ++j)
#pragma unroll
            for (int r = 0; r < 4; ++r)
                tr[(nh + j * 16 + lm) * 136 + (mh + i * 16 + quad * 4 + r)] = f2h(acc[i][j][r]);
    __syncthreads();
    {
        int row = t >> 1, hf = t & 1;
        int mg = n0 + row;
        if (mg < NN) {
#pragma unroll
            for (int q = 0; q < 8; ++q) {
                int cb = m0 + hf * 64 + q * 8;
                if (cb < NN)
                    *(uint4*)(&STh[(long)mg * NR + cb]) =
                        *(const uint4*)(&tr[row * 136 + hf * 64 + q * 8]);
            }
        }
    }
}

// ---------------------------------------------------------------------------
// Merge the NTI per-tile partials -> final (max, 1/sum) per row/col.
// ---------------------------------------------------------------------------
__global__ __launch_bounds__(256)
void stats_final(const float* __restrict__ prm, const float* __restrict__ prs,
                 const float* __restrict__ pcm, const float* __restrict__ pcs,
                 float* __restrict__ rm, float* __restrict__ ri,
                 float* __restrict__ cm, float* __restrict__ ci)
{
    int i = blockIdx.x * 256 + threadIdx.x;
    if (i >= NN) return;
    const float* pm = blockIdx.y ? pcm : prm;
    const float* ps = blockIdx.y ? pcs : prs;
    float m = -3.0e38f, s = 0.f;
#pragma unroll 4
    for (int tI = 0; tI < NTI; ++tI) {
        float m2 = pm[(long)tI * NR + i], s2 = ps[(long)tI * NR + i];
        float M = fmaxf(m, m2);
        s = s * __expf(m - M) + s2 * __expf(m2 - M);
        m = M;
    }
    float inv = 1.f / s;
    if (blockIdx.y) { cm[i] = m; ci[i] = inv; }
    else            { rm[i] = m; ri[i] = inv; }
}

// ---------------------------------------------------------------------------
// Z GEMM with FUSED softmax, BK=128 (round-8 structure, unchanged).
// ---------------------------------------------------------------------------
__global__ __launch_bounds__(256, 2)
void gemm_z_128(const u16* __restrict__ vab_b, const u16* __restrict__ vbb_b,
                const u16* __restrict__ STh, const u16* __restrict__ Sh,
                const float* __restrict__ rm, const float* __restrict__ ri,
                const float* __restrict__ cm, const float* __restrict__ ci,
                float* __restrict__ Zb_b, float* __restrict__ Za_b)
{
    __shared__ u16 As[128 * 128];
    __shared__ u16 Bs[128 * 128];

    const int t = threadIdx.x;
    const int w = t >> 6, lane = t & 63;
    const int mh = (w >> 1) * 64, nh = (w & 1) * 64;
    const int lm = lane & 15, quad = lane >> 4;
    const int n0 = blockIdx.x * 128;
    const int ks = blockIdx.y;                  // 0..3
    const int zz = blockIdx.z;
    const int branch = zz & 1;
    const int m0 = (zz >> 1) * 128;
    const u16* A = branch ? vbb_b : vab_b;
    const u16* B = branch ? Sh : STh;           // raw fp16 S / S^T, stride NR
    const float* mxp = branch ? rm : cm;
    const float* isp = branch ? ri : ci;
    float* Cp = branch ? Za_b : Zb_b;
    const int wb = t & 192;

    const int base = ZKI / ZKS, rem = ZKI % ZKS;   // 7, 1
    const int it0 = ks * base + (ks < rem ? ks : rem);
    const int itn = base + (ks < rem ? 1 : 0);

    // loop-invariant staging geometry: 8 slices over [128 rows][16 chunks].
    int scv[8];
    const u16* Arow[8];
    const u16* Brow[8];
    float bm[8], bi[8];
#pragma unroll
    for (int i = 0; i < 8; ++i) {
        int idx = i * 256 + t;
        int row = idx >> 4, c = idx & 15;
        scv[i] = (c & 8) * 8 + ((c ^ row) & 7) * 8;   // u16 offset in 128-col window
        Arow[i] = A + (long)(m0 + row) * NR + scv[i];
        int rg = n0 + row;
        Brow[i] = B + (long)rg * NR + scv[i];
        int rc = rg < NN ? rg : 0;             // pad rows: value discarded by preds
        bm[i] = mxp[rc];
        bi[i] = isp[rc];
    }

    f32x4 acc[4][4] = {};

    for (int it = it0; it < it0 + itn; ++it) {
        const int k0 = it * 128;
#pragma unroll
        for (int i = 0; i < 8; ++i)
            glds16(Arow[i] + k0, &As[(i * 256 + wb) * 8]);
#pragma unroll
        for (int i = 0; i < 8; ++i) {
            u16 o[8];
            uint4 v = *(const uint4*)(Brow[i] + k0);   // always in-bounds (NRxNR)
            const u16* hp = (const u16*)&v;
            if (k0 + scv[i] < NN) {            // chunk fully < NN (granularity 8)
#pragma unroll
                for (int e = 0; e < 8; ++e)
                    o[e] = f2bf(__expf(h2f(hp[e]) - bm[i]) * bi[i]);
            } else {
#pragma unroll
                for (int e = 0; e < 8; ++e) o[e] = 0;
            }
            *(uint4*)(&Bs[(i * 256 + t) * 8]) = *(const uint4*)o;
        }
        __syncthreads();
#pragma unroll
        for (int s = 0; s < 4; ++s) {          // 4 K-substeps of 32 -> 64 MFMA
            const int sl = ((s >> 1) * 8 + (((s & 1) * 4 + quad) ^ (lm & 7))) * 8;
            short8 a[4], b[4];
#pragma unroll
            for (int i = 0; i < 4; ++i)
                a[i] = *(const short8*)(&As[(mh + i * 16 + lm) * 128 + sl]);
#pragma unroll
            for (int j = 0; j < 4; ++j)
                b[j] = *(const short8*)(&Bs[(nh + j * 16 + lm) * 128 + sl]);
#pragma unroll
            for (int i = 0; i < 4; ++i)
#pragma unroll
                for (int j = 0; j < 4; ++j)
                    acc[i][j] = __builtin_amdgcn_mfma_f32_16x16x32_bf16(a[i], b[j], acc[i][j], 0, 0, 0);
        }
        __syncthreads();
    }

#pragma unroll
    for (int i = 0; i < 4; ++i)
#pragma unroll
        for (int r = 0; r < 4; ++r) {
            int row = m0 + mh + i * 16 + quad * 4 + r;
#pragma unroll
            for (int j = 0; j < 4; ++j) {
                int col = n0 + nh + j * 16 + lm;
                if (col < NN)
                    atomicAdd(&Cp[(long)row * NN + col], acc[i][j][r]);
            }
        }
}

// ---------------------------------------------------------------------------
// Both direct convs, one launch, XCD-grouped remap: combo = L % 8,
// (p-tile, ks) = L / 8  (round-5 mapping, FROZEN). BK=64 (round-8 version,
// measured 3x at 88.5-89 us, FETCH = compulsory 25 MB, conflicts 0; the
// BK=128 variant regressed: broke dw tap reuse + conflicts + residency tail).
// Split-K CZKS=3 (slice == one dh row, dh block-constant); dw-innermost
// K-order (weights permuted); per-(i,dw) validity hoisted; zbuf redirect.
// ---------------------------------------------------------------------------
__global__ __launch_bounds__(256, 4)
void conv_both(const u16* __restrict__ W1, const u16* __restrict__ W2,
               const u16* __restrict__ gzaT, const u16* __restrict__ vat,
               const u16* __restrict__ daT, const u16* __restrict__ gzbT,
               const u16* __restrict__ vbt, const u16* __restrict__ zbuf,
               float* __restrict__ y1, float* __restrict__ y2)
{
    __shared__ u16 As[128 * 64];
    __shared__ u16 Bs[128 * 64];

    const int t = threadIdx.x;
    const int w = t >> 6, lane = t & 63;
    const int mh = (w >> 1) * 64, nh = (w & 1) * 64;
    const int lm = lane & 15, quad = lane >> 4;
    const int wb = t & 192;

    const long L = blockIdx.x + (long)NTI * (blockIdx.y + (long)CZKS * blockIdx.z);
    const int combo = (int)(L & 7);
    const long rest = L >> 3;                   // 0..86
    const int ks = (int)(rest % CZKS);
    const int px = (int)(rest / CZKS);          // 0..28
    const int which = combo >> 2;
    const int b = (combo >> 1) & 1;
    const int m0 = (combo & 1) * 128;
    const int n0 = px * 128;

    const int CIN = which ? 512 : 768;
    const int KT = 9 * CIN;
    const u16* W = which ? W2 : W1;
    const u16* P0 = which ? gzbT : gzaT;
    const u16* P1 = which ? vbt : vat;
    const u16* P2 = which ? vbt : daT;
    float* Y = which ? y2 : y1;
    const long pstride = (long)NR * CC;

    const int PER = 3 * (CIN / 64);             // 36 or 24 (64-col groups/slice)
    const int it0 = ks * PER;
    const int dh = ks - 1;                      // block-constant

    // hoisted per-lane staging geometry + per-(i,dw) validity
    int rowv[4], sc8v[4], rb[4];
    bool okd[4][3];
#pragma unroll
    for (int i = 0; i < 4; ++i) {
        int idx = i * 256 + t;
        int row = idx >> 3;
        rowv[i] = row;
        sc8v[i] = ((idx ^ row) & 7) * 8;
        int pq = n0 + row;
        int h = pq / 60, wp = pq - h * 60;
        rb[i] = (pq + dh * 60) * CC + sc8v[i];
        bool hok = (pq < NN) && ((unsigned)(h + dh) < 60u);
#pragma unroll
        for (int d = 0; d < 3; ++d)
            okd[i][d] = hok && ((unsigned)(wp + d - 1) < 60u);
    }

    f32x4 acc[4][4] = {};

    for (int it = it0; it < it0 + PER; ++it) {
        const int k0 = it * 64;                 // weight column (permuted layout)
        const int g = it - it0;
        const int dw = g % 3;                   // innermost: adjacent window reuse
        const int pc = g / 3;
        const int plane = pc >> 2;
        const int cip = (pc & 3) * 64;
        const u16* srcp = ((plane == 0) ? P0 : (plane == 1) ? P1 : P2)
                          + (long)b * pstride + cip;

#pragma unroll
        for (int i = 0; i < 4; ++i) {
            glds16(W + (long)(m0 + rowv[i]) * KT + k0 + sc8v[i], &As[(i * 256 + wb) * 8]);
            const u16* gs = okd[i][dw] ? srcp + rb[i] + (dw - 1) * CC : zbuf;
            glds16(gs, &Bs[(i * 256 + wb) * 8]);
        }
        __syncthreads();
#pragma unroll
        for (int s = 0; s < 2; ++s) {
            short8 a[4], bfr[4];
#pragma unroll
            for (int i = 0; i < 4; ++i)
                a[i] = *(const short8*)(&As[(mh + i * 16 + lm) * 64 + ((s * 4 + quad) ^ (lm & 7)) * 8]);
#pragma unroll
            for (int j = 0; j < 4; ++j)
                bfr[j] = *(const short8*)(&Bs[(nh + j * 16 + lm) * 64 + ((s * 4 + quad) ^ (lm & 7)) * 8]);
#pragma unroll
            for (int i = 0; i < 4; ++i)
#pragma unroll
                for (int j = 0; j < 4; ++j)
                    acc[i][j] = __builtin_amdgcn_mfma_f32_16x16x32_bf16(a[i], bfr[j], acc[i][j], 0, 0, 0);
        }
        __syncthreads();
    }

    float* out = Y + (long)b * CC * NN;
#pragma unroll
    for (int i = 0; i < 4; ++i)
#pragma unroll
        for (int r = 0; r < 4; ++r) {
            int row = m0 + mh + i * 16 + quad * 4 + r;
#pragma unroll
            for (int j = 0; j < 4; ++j) {
                int col = n0 + nh + j * 16 + lm;
                if (col < NN)
                    atomicAdd(&out[(long)row * NN + col], acc[i][j][r]);
            }
        }
}

// ---------------------------------------------------------------------------
// Converters / transposes
// ---------------------------------------------------------------------------
__global__ __launch_bounds__(256)
void cvt_we(const float* __restrict__ W, u16* __restrict__ O)
{
    int i = blockIdx.x * 256 + threadIdx.x;
    if (i < CC * CC) O[i] = f2bf(W[i]);
}

// All three input transposes in one launch: z -> (src, batch).
// V [b][256][3600] fp32 -> VT [b][3712][256] bf16 (+ optional NR-padded copy
// with zeroed cols 3600..3712 for gemm_z's BK=128). grid.x = 58.
__global__ __launch_bounds__(256)
void transpose_cvt3(const float* __restrict__ Va, const float* __restrict__ Vb,
                    const float* __restrict__ Da,
                    u16* __restrict__ vat, u16* __restrict__ vbt,
                    u16* __restrict__ daT,
                    u16* __restrict__ vab, u16* __restrict__ vbb)
{
    __shared__ float tile[64][65];
    int z = blockIdx.z;
    int s = z % 3, b = z / 3;
    const float* V = (s == 0) ? Va : (s == 1) ? Vb : Da;
    u16* VT = (s == 0) ? vat : (s == 1) ? vbt : daT;
    u16* Vpad = (s == 0) ? vab : (s == 1) ? vbb : nullptr;

    int c0 = blockIdx.y * 64, n0 = blockIdx.x * 64;
    int t = threadIdx.x;
#pragma unroll
    for (int e = 0; e < 16; ++e) {
        int f = e * 256 + t; int i = f >> 6, j = f & 63;
        int n = n0 + j;
        float v = 0.f;
        if (n < NN) v = V[((long)b * CC + c0 + i) * NN + n];
        tile[i][j] = v;
        if (Vpad) Vpad[((long)b * CC + c0 + i) * NR + n] = f2bf(v);
    }
    __syncthreads();
#pragma unroll
    for (int e = 0; e < 16; ++e) {
        int f = e * 256 + t; int i = f >> 6, j = f & 63;
        int n = n0 + i;
        if (n < NN) VT[((long)b * NR + n) * CC + c0 + j] = f2bf(tile[j][i]);
    }
}

// conv weight convert with dw-innermost K permutation (matches conv_both):
// column c64 = ks*PER + pc*3 + dw, where tap = ks*3+dw, ci = pc*64 + within.
template<int CIN>
__global__ __launch_bounds__(256)
void cvt_convw(const float* __restrict__ W, u16* __restrict__ O)
{
    const int KT = 9 * CIN;
    const int PER = 3 * (CIN / 64);
    long idx = (long)blockIdx.x * 256 + threadIdx.x;
    if (idx >= (long)CC * KT) return;
    int co = (int)(idx / KT);
    int r = (int)(idx % KT);
    int c64 = r >> 6, within = r & 63;
    int ks = c64 / PER, g = c64 % PER;
    int dw = g % 3, pc = g / 3;
    int tap = ks * 3 + dw;
    int ci = pc * 64 + within;
    O[idx] = f2bf(W[((long)co * CIN + ci) * 9 + tap]);
}

// ---------------------------------------------------------------------------
// FUSED per-pixel gate + transpose-scale: one pass computes
// sg[p] = sigmoid(sum_c gw[c]*Z[c,p]) for the block's 64 pixels, then the
// 4 transpose sub-tiles re-read the block's 64 KB window (L2-hot) and write
// ZT[b][p][c] = bf16(Z[c,p] * sg[p]). blockIdx.y: b = y&1, side = y>>1.
// ---------------------------------------------------------------------------
__global__ __launch_bounds__(256)
void gate_transpose(const float* __restrict__ Za, const float* __restrict__ Zb,
                    const float* __restrict__ gw,
                    u16* __restrict__ gzaT, u16* __restrict__ gzbT)
{
    __shared__ float tile[64][65];
    __shared__ float red[256];
    __shared__ float sgs[64];

    int zy = blockIdx.y;
    int b = zy & 1, ab = zy >> 1;
    const float* Z = ab ? Zb : Za;
    u16* ZT = ab ? gzbT : gzaT;
    int n0 = blockIdx.x * 64;
    int t = threadIdx.x;
    int px = t & 63, ck = t >> 6;
    const float* Zp = Z + (long)b * CC * NN;

    // gate reduction (all 256 channels across 4 thread-groups)
    float g = 0.f;
    int p = n0 + px;
    if (p < NN) {
        for (int c = ck * 64; c < ck * 64 + 64; ++c) g += gw[c] * Zp[(long)c * NN + p];
    }
    red[t] = g;
    __syncthreads();
    if (t < 64) {
        float tot = red[t] + red[t + 64] + red[t + 128] + red[t + 192];
        sgs[t] = 1.f / (1.f + __expf(-tot));
    }

    // 4 transpose sub-tiles (re-read through L2)
    for (int c0 = 0; c0 < CC; c0 += 64) {
        __syncthreads();
#pragma unroll
        for (int e = 0; e < 16; ++e) {
            int f = e * 256 + t; int i = f >> 6, j = f & 63;
            int n = n0 + j;
            float v = 0.f;
            if (n < NN) v = Zp[(long)(c0 + i) * NN + n];
            tile[i][j] = v;
        }
        __syncthreads();
#pragma unroll
        for (int e = 0; e < 16; ++e) {
            int f = e * 256 + t; int i = f >> 6, j = f & 63;
            int n = n0 + i;
            if (n < NN)
                ZT[((long)b * NR + n) * CC + c0 + j] = f2bf(tile[j][i] * sgs[i]);
        }
    }
}

// ---------------------------------------------------------------------------
// BatchNorm batch-stats -> scale/shift, both branches (x = which*256 + c)
// ---------------------------------------------------------------------------
__global__ __launch_bounds__(256)
void bn_stats_kernel(const float* __restrict__ y1, const float* __restrict__ y2,
                     const float* __restrict__ g1, const float* __restrict__ b1,
                     const float* __restrict__ g2, const float* __restrict__ b2,
                     float* __restrict__ sc1, float* __restrict__ sh1,
                     float* __restrict__ sc2, float* __restrict__ sh2)
{
    int which = blockIdx.x >> 8;
    int c = blockIdx.x & 255, t = threadIdx.x;
    const float* Y = which ? y2 : y1;
    const float* g = which ? g2 : g1;
    const float* beta = which ? b2 : b1;
    float* scale = which ? sc2 : sc1;
    float* shift = which ? sh2 : sh1;
    float s = 0.f, sq = 0.f;
    for (int b = 0; b < BB; ++b) {
        const float* p = Y + (long)b * CC * NN + (long)c * NN;
        for (int i = t; i < NN; i += 256) { float v = p[i]; s += v; sq += v * v; }
    }
    __shared__ float ls[256], lq[256];
    ls[t] = s; lq[t] = sq;
    __syncthreads();
    for (int off = 128; off > 0; off >>= 1) {
        if (t < off) { ls[t] += ls[t + off]; lq[t] += lq[t + off]; }
        __syncthreads();
    }
    if (t == 0) {
        const float inv = 1.f / (float)(BB * NN);
        float mean = ls[0] * inv;
        float var = fmaxf(lq[0] * inv - mean * mean, 0.f);
        float sc = g[c] * rsqrtf(var + 1e-5f);
        scale[c] = sc;
        shift[c] = beta[c] - mean * sc;
    }
}

// ---------------------------------------------------------------------------
// Fused BN-normalize + ReLU + 1x1 cls conv + bias, both branches (z = which)
// ---------------------------------------------------------------------------
__global__ __launch_bounds__(256)
void cls_kernel(const float* __restrict__ y1, const float* __restrict__ y2,
                const float* __restrict__ sc1, const float* __restrict__ sh1,
                const float* __restrict__ sc2, const float* __restrict__ sh2,
                const float* __restrict__ cw1, const float* __restrict__ cb1,
                const float* __restrict__ cw2, const float* __restrict__ cb2,
                float* __restrict__ O1, float* __restrict__ O2)
{
    int which = blockIdx.z;
    const float* Y = which ? y2 : y1;
    const float* scale = which ? sc2 : sc1;
    const float* shift = which ? sh2 : sh1;
    const float* cw = which ? cw2 : cw1;
    const float* cb = which ? cb2 : cb1;
    float* O = which ? O2 : O1;

    int t = threadIdx.x;
    int px = t & 63, ck = t >> 6;
    int b = blockIdx.y;
    int p = blockIdx.x * 64 + px;
    const float* Yb = Y + (long)b * CC * NN;
    float a0 = 0.f, a1 = 0.f;
    if (p < NN) {
        for (int c = ck * 64; c < ck * 64 + 64; ++c) {
            float v = Yb[(long)c * NN + p] * scale[c] + shift[c];
            v = fmaxf(v, 0.f);
            a0 += cw[c] * v;
            a1 += cw[CC + c] * v;
        }
    }
    __shared__ float r0[256], r1[256];
    r0[t] = a0; r1[t] = a1;
    __syncthreads();
    if (t < 64) {
        int pp = blockIdx.x * 64 + t;
        if (pp < NN) {
            float s0 = r0[t] + r0[t + 64] + r0[t + 128] + r0[t + 192];
            float s1 = r1[t] + r1[t + 64] + r1[t + 128] + r1[t + 192];
            O[(long)b * NCH * NN + pp] = s0 + cb[0];
            O[(long)b * NCH * NN + NN + pp] = s1 + cb[1];
        }
    }
}

// ---------------------------------------------------------------------------
// Bilinear resize 60x60 -> 473x473 (half-pixel, clamp) + sigmoid
// ---------------------------------------------------------------------------
__global__ __launch_bounds__(256)
void resize_sig_kernel(const float* __restrict__ I1, const float* __restrict__ I2,
                       float* __restrict__ O)
{
    const long HALF = (long)BB * NCH * HO * WO;
    long gid = (long)blockIdx.x * 256 + threadIdx.x;
    if (gid >= HALF) return;
    int half = blockIdx.y;
    const float* I = half ? I2 : I1;
    float* Op = O + half * HALF;

    int j = (int)(gid % WO);
    long r = gid / WO;
    int i = (int)(r % HO);
    int pc = (int)(r / HO);
    const float* ip = I + (long)pc * NN;

    const float SCL = 60.0f / 473.0f;
    float fy = (i + 0.5f) * SCL - 0.5f;
    float fx = (j + 0.5f) * SCL - 0.5f;
    int y0 = (int)floorf(fy);
    int x0 = (int)floorf(fx);
    float ty = fy - (float)y0;
    float tx = fx - (float)x0;
    int y0c = max(y0, 0), y1c = min(y0 + 1, 59);
    int x0c = max(x0, 0), x1c = min(x0 + 1, 59);
    float va = ip[y0c * 60 + x0c], vb = ip[y0c * 60 + x1c];
    float vc = ip[y1c * 60 + x0c], vd = ip[y1c * 60 + x1c];
    float v = (1.f - ty) * ((1.f - tx) * va + tx * vb) + ty * ((1.f - tx) * vc + tx * vd);
    Op[gid] = 1.f / (1.f + __expf(-v));
}

// ---------------------------------------------------------------------------
extern "C" void kernel_launch(void* const* d_in, const int* in_sizes, int n_in,
                              void* d_out, int out_size, void* d_ws, size_t ws_size,
                              hipStream_t stream)
{
    const float* V_a    = (const float*)d_in[0];
    const float* V_b    = (const float*)d_in[1];
    const float* D_a    = (const float*)d_in[2];
    const float* W_e    = (const float*)d_in[3];
    const float* gate_w = (const float*)d_in[4];
    const float* conv1_w = (const float*)d_in[5];
    const float* conv2_w = (const float*)d_in[6];
    const float* bn1_g = (const float*)d_in[7];
    const float* bn1_b = (const float*)d_in[8];
    const float* bn2_g = (const float*)d_in[9];
    const float* bn2_b = (const float*)d_in[10];
    const float* cls1_w = (const float*)d_in[11];
    const float* cls1_b = (const float*)d_in[12];
    const float* cls2_w = (const float*)d_in[13];
    const float* cls2_b = (const float*)d_in[14];
    float* out = (float*)d_out;

    // ---- workspace arena (~124 MB; known-safe bound: 154.9 MB) ----
    size_t off = 0;
    char* wsb = (char*)d_ws;
    auto carve = [&](size_t bytes) -> char* {
        char* p = wsb + off; off += (bytes + 255) & ~(size_t)255; return p;
    };

    u16* Sh    = (u16*)carve((size_t)NR * NR * 2);         // 27.6 MB, per-batch (raw S)
    u16* STh   = (u16*)carve((size_t)NR * NR * 2);         // 27.6 MB, per-batch (raw S^T)
    u16* vab   = (u16*)carve((size_t)BB * CC * NR * 2);    // K padded to NR, pads zeroed
    u16* vbb   = (u16*)carve((size_t)BB * CC * NR * 2);
    u16* vat   = (u16*)carve((size_t)BB * NR * CC * 2);
    u16* vbt   = (u16*)carve((size_t)BB * NR * CC * 2);
    u16* daT   = (u16*)carve((size_t)BB * NR * CC * 2);
    u16* gzaT  = (u16*)carve((size_t)BB * NR * CC * 2);
    u16* gzbT  = (u16*)carve((size_t)BB * NR * CC * 2);
    u16* wgtb  = (u16*)carve((size_t)BB * NR * CC * 2);
    u16* zbuf  = (u16*)carve(256);
    u16* web   = (u16*)carve((size_t)CC * CC * 2);
    u16* wt1   = (u16*)carve((size_t)CC * 9 * 768 * 2);
    u16* wt2   = (u16*)carve((size_t)CC * 9 * 512 * 2);
    float* Za  = (float*)carve((size_t)BB * CC * NN * 4);  // contiguous 4-block
    float* Zb  = (float*)carve((size_t)BB * CC * NN * 4);  //   memset region
    float* y1  = (float*)carve((size_t)BB * CC * NN * 4);
    float* y2  = (float*)carve((size_t)BB * CC * NN * 4);
    float* rmx = (float*)carve((size_t)BB * NN * 4);       // row max   (later BN sc1)
    float* rsm = (float*)carve((size_t)BB * NN * 4);       // row 1/sum (later BN sh1)
    float* cmx = (float*)carve((size_t)BB * NN * 4);       // col max   (later BN sc2)
    float* csm = (float*)carve((size_t)BB * NN * 4);       // col 1/sum (later BN sh2)
    float* prm = (float*)carve((size_t)NTI * NR * 4);
    float* prs = (float*)carve((size_t)NTI * NR * 4);
    float* pcm = (float*)carve((size_t)NTI * NR * 4);
    float* pcs = (float*)carve((size_t)NTI * NR * 4);
    float* c1o = (float*)carve((size_t)BB * NCH * NN * 4);
    float* c2o = (float*)carve((size_t)BB * NCH * NN * 4);

    dim3 blk(256);

    // zero-init atomic accumulators (Za,Zb,y1,y2 contiguous) + zbuf.
    // Pad rows of the transposed arenas are NOT zeroed — all consumers of
    // pad garbage are predicated (audited round 6).
    hipMemsetAsync(Za, 0, (size_t)4 * BB * CC * NN * 4, stream);
    hipMemsetAsync(zbuf, 0, 256, stream);

    // --- input conversions (merged; padded copies fused into transposes) ---
    cvt_we<<<256, blk, 0, stream>>>(W_e, web);
    transpose_cvt3<<<dim3(58, 4, 3 * BB), blk, 0, stream>>>(
        V_a, V_b, D_a, vat, vbt, daT, vab, vbb);
    cvt_convw<768><<<(int)(((long)CC * 9 * 768 + 255) / 256), blk, 0, stream>>>(conv1_w, wt1);
    cvt_convw<512><<<(int)(((long)CC * 9 * 512 + 255) / 256), blk, 0, stream>>>(conv2_w, wt2);

    // --- weighted (both batches) ---
    gemm_we<<<dim3(2, NTI, BB), blk, 0, stream>>>(vat, web, wgtb);

    // --- attention, per batch: S+stats -> final stats -> fused-softmax Z ---
    for (int b = 0; b < BB; ++b) {
        const u16* wgtb_b = wgtb + (long)b * NR * CC;
        const u16* vbt_b  = vbt + (long)b * NR * CC;
        const u16* vab_b  = vab + (long)b * CC * NR;
        const u16* vbb_b  = vbb + (long)b * CC * NR;
        float* rmx_b = rmx + b * NN; float* rsm_b = rsm + b * NN;
        float* cmx_b = cmx + b * NN; float* csm_b = csm + b * NN;

        gemm_s_stats<<<dim3(NTI, NTI), blk, 0, stream>>>(
            wgtb_b, vbt_b, Sh, STh, prm, prs, pcm, pcs);
        stats_final<<<dim3((NN + 255) / 256, 2), blk, 0, stream>>>(
            prm, prs, pcm, pcs, rmx_b, rsm_b, cmx_b, csm_b);
        gemm_z_128<<<dim3(NTI, ZKS, 4), blk, 0, stream>>>(
            vab_b, vbb_b, STh, Sh, rmx_b, rsm_b, cmx_b, csm_b,
            Zb + (long)b * CC * NN, Za + (long)b * CC * NN);
    }

    // --- fused gate sigmoid + transpose-scale to [p][c] bf16 ---
    gate_transpose<<<dim3(57, 2 * BB), blk, 0, stream>>>(
        Za, Zb, gate_w, gzaT, gzbT);

    // --- both convs, one launch, BK=64, XCD-grouped remap, atomic y1/y2 ---
    conv_both<<<dim3(NTI, CZKS, 8), blk, 0, stream>>>(
        wt1, wt2, gzaT, vat, daT, gzbT, vbt, zbuf, y1, y2);

    // --- BN + cls + resize --- (rmx/rsm/cmx/csm reused as scale/shift)
    bn_stats_kernel<<<2 * CC, blk, 0, stream>>>(
        y1, y2, bn1_g, bn1_b, bn2_g, bn2_b, rmx, rsm, cmx, csm);
    cls_kernel<<<dim3(57, BB, 2), blk, 0, stream>>>(
        y1, y2, rmx, rsm, cmx, csm, cls1_w, cls1_b, cls2_w, cls2_b, c1o, c2o);

    resize_sig_kernel<<<dim3((int)(((long)BB * NCH * HO * WO + 255) / 256), 2), blk, 0, stream>>>(c1o, c2o, out);
}